// Round 7
// baseline (447.130 us; speedup 1.0000x reference)
//
#include <hip/hip_runtime.h>
#include <math.h>

#define D_FEAT 128
#define BM 128
#define BN 128
#define BK 32
#define SCAN_ITEMS 2048   // items per scan block (256 thr * 8)

// setup: zero histogram counters + transpose W -> Wt [256 k][128 n]
__global__ __launch_bounds__(256) void setup_kernel(const float* __restrict__ W,
                                                    float* __restrict__ Wt,
                                                    int* __restrict__ cnt, int M) {
    int i = blockIdx.x * 256 + threadIdx.x;
    if (i < 2 * D_FEAT * D_FEAT) {
        int k = i >> 7, d = i & (D_FEAT - 1);
        Wt[i] = W[(size_t)d * (2 * D_FEAT) + k];
    }
    if (i < M) cnt[i] = 0;
}

// 1) histogram of segment ids (int4 loads)
__global__ __launch_bounds__(256) void hist_kernel(const int* __restrict__ index,
                                                   int* __restrict__ cnt, int n4, int n) {
    int i = blockIdx.x * 256 + threadIdx.x;
    if (i < n4) {
        int4 v = reinterpret_cast<const int4*>(index)[i];
        atomicAdd(&cnt[v.x], 1);
        atomicAdd(&cnt[v.y], 1);
        atomicAdd(&cnt[v.z], 1);
        atomicAdd(&cnt[v.w], 1);
    }
    int rem = 4 * n4 + i;           // tail (none for n%4==0)
    if (i < n - 4 * n4) atomicAdd(&cnt[index[rem]], 1);
}

// 2a) per-block sums of cnt (coalesced)
__global__ __launch_bounds__(256) void blocksum_kernel(const int* __restrict__ cnt,
                                                       int* __restrict__ bsum, int n) {
    __shared__ int sh[256];
    const int b = blockIdx.x, t = threadIdx.x;
    const int base = b * SCAN_ITEMS;
    int s = 0;
    #pragma unroll
    for (int j = 0; j < 8; ++j) {
        int i = base + j * 256 + t;
        if (i < n) s += cnt[i];
    }
    sh[t] = s;
    __syncthreads();
    for (int st = 128; st > 0; st >>= 1) {
        if (t < st) sh[t] += sh[t + st];
        __syncthreads();
    }
    if (t == 0) bsum[b] = sh[0];
}

// 2b) single-wave scan of block sums (nblk <= 64); also writes off[n] = total
__global__ __launch_bounds__(64) void scanblk_kernel(const int* __restrict__ bsum,
                                                     int* __restrict__ boff,
                                                     int* __restrict__ off,
                                                     int n, int nblk) {
    int t = threadIdx.x;
    int v = (t < nblk) ? bsum[t] : 0;
    int orig = v;
    #pragma unroll
    for (int d = 1; d < 64; d <<= 1) {
        int u = __shfl_up(v, d);
        if (t >= d) v += u;
    }
    if (t < nblk) boff[t] = v - orig;   // exclusive
    if (t == 63) off[n] = v;            // grand total
}

// 2c) apply: per-block exclusive scan over its 2048 items -> off, cursor
__global__ __launch_bounds__(256) void apply_kernel(const int* __restrict__ cnt,
                                                    const int* __restrict__ boff,
                                                    int* __restrict__ off,
                                                    int* __restrict__ cursor, int n) {
    __shared__ int sh[SCAN_ITEMS];
    __shared__ int ts[256];
    const int b = blockIdx.x, t = threadIdx.x;
    const int base = b * SCAN_ITEMS;
    #pragma unroll
    for (int j = 0; j < 8; ++j) {
        int i = base + j * 256 + t;
        sh[j * 256 + t] = (i < n) ? cnt[i] : 0;
    }
    __syncthreads();
    int s = 0;
    #pragma unroll
    for (int j = 0; j < 8; ++j) s += sh[t * 8 + j];
    ts[t] = s;
    __syncthreads();
    for (int st = 1; st < 256; st <<= 1) {
        int u = (t >= st) ? ts[t - st] : 0;
        __syncthreads();
        ts[t] += u;
        __syncthreads();
    }
    int run = boff[b] + ts[t] - s;      // exclusive prefix for this thread's chunk
    #pragma unroll
    for (int j = 0; j < 8; ++j) {
        int i = base + t * 8 + j;
        if (i < n) {
            off[i] = run;
            cursor[i] = run;
            run += sh[t * 8 + j];
        }
    }
}

// 3) scatter edge ids into segment-sorted order (int4 loads)
__global__ __launch_bounds__(256) void order_kernel(const int* __restrict__ index,
                                                    int* __restrict__ cursor,
                                                    int* __restrict__ order, int n4, int n) {
    int i = blockIdx.x * 256 + threadIdx.x;
    if (i < n4) {
        int4 v = reinterpret_cast<const int4*>(index)[i];
        int e = 4 * i;
        order[atomicAdd(&cursor[v.x], 1)] = e;
        order[atomicAdd(&cursor[v.y], 1)] = e + 1;
        order[atomicAdd(&cursor[v.z], 1)] = e + 2;
        order[atomicAdd(&cursor[v.w], 1)] = e + 3;
    }
    int rem = 4 * n4 + i;
    if (i < n - 4 * n4) order[atomicAdd(&cursor[index[rem]], 1)] = rem;
}

// 4) one wave per segment, WAVE-UNIFORM broadcast-gather:
//    - coalesced 64-wide load of the segment's order[] chunk
//    - uniform j loop: all lanes gather the SAME src row (lane owns 2 features
//      -> 64 lanes x 8B = one 512B row per gather, perfectly coalesced)
//    - two accumulator sets (even/odd rows) break the dependence chain
__global__ __launch_bounds__(256) void reduce_kernel(
    const float* __restrict__ src, const int* __restrict__ order,
    const int* __restrict__ off, float* __restrict__ A, int nseg)
{
    int wid  = (blockIdx.x * 256 + threadIdx.x) >> 6;
    int lane = threadIdx.x & 63;
    if (wid >= nseg) return;

    const int start = off[wid], end = off[wid + 1];
    const int fo = lane * 2;   // feature offset 0..126

    float2 s0 = make_float2(0.f, 0.f), s1 = make_float2(0.f, 0.f);
    float2 m0 = make_float2(-INFINITY, -INFINITY), m1 = m0;

    for (int base = start; base < end; base += 64) {
        int idx = base + lane;
        int eo  = (idx < end) ? order[idx] : 0;      // coalesced 256B wave load
        int lim = end - base; if (lim > 64) lim = 64;
        int j = 0;
        #pragma unroll 2
        for (; j + 1 < lim; j += 2) {
            int e0 = __shfl(eo, j);
            int e1 = __shfl(eo, j + 1);
            float2 v0 = *reinterpret_cast<const float2*>(src + (size_t)e0 * D_FEAT + fo);
            float2 v1 = *reinterpret_cast<const float2*>(src + (size_t)e1 * D_FEAT + fo);
            s0.x += v0.x; s0.y += v0.y;
            s1.x += v1.x; s1.y += v1.y;
            m0.x = fmaxf(m0.x, v0.x); m0.y = fmaxf(m0.y, v0.y);
            m1.x = fmaxf(m1.x, v1.x); m1.y = fmaxf(m1.y, v1.y);
        }
        if (j < lim) {
            int e0 = __shfl(eo, j);
            float2 v0 = *reinterpret_cast<const float2*>(src + (size_t)e0 * D_FEAT + fo);
            s0.x += v0.x; s0.y += v0.y;
            m0.x = fmaxf(m0.x, v0.x); m0.y = fmaxf(m0.y, v0.y);
        }
    }

    float2 sum = make_float2(s0.x + s1.x, s0.y + s1.y);
    float2 mx  = make_float2(fmaxf(m0.x, m1.x), fmaxf(m0.y, m1.y));
    if (end == start) { mx.x = 0.f; mx.y = 0.f; }   // empty segment -> 0

    float* row = A + (size_t)wid * (2 * D_FEAT);
    *reinterpret_cast<float2*>(row + fo)          = sum;
    *reinterpret_cast<float2*>(row + D_FEAT + fo) = mx;
}

// 5) out[M,128] = A[M,256] * Wt[256,128] + bias
__global__ __launch_bounds__(256) void gemm_kernel(
    const float* __restrict__ A, const float* __restrict__ Wt,
    const float* __restrict__ bias, float* __restrict__ out, int M)
{
    __shared__ float As[BK][BM + 4];   // row stride 132 floats (float4-aligned)
    __shared__ float Bs[BK][BN];

    const int t = threadIdx.x;
    const int m_base = blockIdx.x * BM;
    const int ty = t >> 4, tx = t & 15;
    const int trow = ty * 8, tcol = tx * 8;

    float acc[8][8] = {};

    for (int k0 = 0; k0 < 2 * D_FEAT; k0 += BK) {
        #pragma unroll
        for (int p = 0; p < 4; ++p) {
            int m  = p * 32 + (t >> 3);
            int kv = (t & 7) << 2;
            int gm = m_base + m;
            float4 v = make_float4(0.f, 0.f, 0.f, 0.f);
            if (gm < M)
                v = *reinterpret_cast<const float4*>(A + (size_t)gm * (2 * D_FEAT) + k0 + kv);
            As[kv + 0][m] = v.x;
            As[kv + 1][m] = v.y;
            As[kv + 2][m] = v.z;
            As[kv + 3][m] = v.w;
        }
        #pragma unroll
        for (int p = 0; p < 4; ++p) {
            int k  = p * 8 + (t >> 5);
            int nv = (t & 31) << 2;
            *reinterpret_cast<float4*>(&Bs[k][nv]) =
                *reinterpret_cast<const float4*>(Wt + (size_t)(k0 + k) * BN + nv);
        }
        __syncthreads();

        #pragma unroll
        for (int k = 0; k < BK; ++k) {
            float4 a0 = *reinterpret_cast<const float4*>(&As[k][trow]);
            float4 a1 = *reinterpret_cast<const float4*>(&As[k][trow + 4]);
            float4 b0 = *reinterpret_cast<const float4*>(&Bs[k][tcol]);
            float4 b1 = *reinterpret_cast<const float4*>(&Bs[k][tcol + 4]);
            float a[8] = {a0.x, a0.y, a0.z, a0.w, a1.x, a1.y, a1.z, a1.w};
            float bb[8] = {b0.x, b0.y, b0.z, b0.w, b1.x, b1.y, b1.z, b1.w};
            #pragma unroll
            for (int i = 0; i < 8; ++i)
                #pragma unroll
                for (int j = 0; j < 8; ++j)
                    acc[i][j] += a[i] * bb[j];
        }
        __syncthreads();
    }

    #pragma unroll
    for (int i = 0; i < 8; ++i) {
        int gm = m_base + trow + i;
        if (gm >= M) continue;
        #pragma unroll
        for (int j = 0; j < 8; j += 4) {
            float4 r;
            r.x = acc[i][j + 0] + bias[tcol + j + 0];
            r.y = acc[i][j + 1] + bias[tcol + j + 1];
            r.z = acc[i][j + 2] + bias[tcol + j + 2];
            r.w = acc[i][j + 3] + bias[tcol + j + 3];
            *reinterpret_cast<float4*>(out + (size_t)gm * BN + tcol + j) = r;
        }
    }
}

extern "C" void kernel_launch(void* const* d_in, const int* in_sizes, int n_in,
                              void* d_out, int out_size, void* d_ws, size_t ws_size,
                              hipStream_t stream) {
    const float* src   = (const float*)d_in[0];
    const int*   index = (const int*)d_in[1];
    const float* W     = (const float*)d_in[2];
    const float* bias  = (const float*)d_in[3];

    const int n_edges = in_sizes[1];            // 1,600,000
    const int M       = out_size / D_FEAT;      // 50,000 (dim_size)

    // workspace layout
    float* A      = (float*)d_ws;                     // M * 256 f32
    float* Wt     = A + (size_t)M * 2 * D_FEAT;       // 256*128 f32
    int*   cnt    = (int*)(Wt + 2 * D_FEAT * D_FEAT); // M
    int*   off    = cnt + M;                          // M + 1
    int*   cursor = off + M + 1;                      // M
    int*   order  = cursor + M;                       // n_edges
    int*   bsum   = order + n_edges;                  // <= 64
    int*   boff   = bsum + 64;                        // <= 64

    const int nblk = (M + SCAN_ITEMS - 1) / SCAN_ITEMS;   // 25 for M=50000

    setup_kernel<<<(max(M, 2 * D_FEAT * D_FEAT) + 255) / 256, 256, 0, stream>>>(W, Wt, cnt, M);

    int n4 = n_edges / 4;
    int eb4 = (max(n4, n_edges - 4 * n4) + 255) / 256;
    hist_kernel<<<eb4, 256, 0, stream>>>(index, cnt, n4, n_edges);

    blocksum_kernel<<<nblk, 256, 0, stream>>>(cnt, bsum, M);
    scanblk_kernel<<<1, 64, 0, stream>>>(bsum, boff, off, M, nblk);
    apply_kernel<<<nblk, 256, 0, stream>>>(cnt, boff, off, cursor, M);

    order_kernel<<<eb4, 256, 0, stream>>>(index, cursor, order, n4, n_edges);

    int rb = (M * 64 + 255) / 256;
    reduce_kernel<<<rb, 256, 0, stream>>>(src, order, off, A, M);

    gemm_kernel<<<(M + BM - 1) / BM, 256, 0, stream>>>(A, Wt, bias, (float*)d_out, M);
}